// Round 1
// baseline (144.623 us; speedup 1.0000x reference)
//
#include <hip/hip_runtime.h>

#define K_IN 76      // input feature dim
#define DD 84        // augmented dim
#define LDA 85       // padded LDS leading dim
#define HCH 128      // penultimate width
#define CCH 5        // classes
#define NTOK 65536   // 32*2048 tokens
#define HSTEP 0.05f  // 1/20

// ---------------- 84x84 matmul helpers (one workgroup, LDS operands) -------
__device__ __forceinline__ void mm84(const float* __restrict__ Am,
                                     const float* __restrict__ Bm,
                                     const int* ri, const int* ci,
                                     float* __restrict__ R)
{
#pragma unroll
    for (int i = 0; i < 36; ++i) R[i] = 0.f;
    for (int k = 0; k < DD; ++k) {
        float av[6], bv[6];
#pragma unroll
        for (int a = 0; a < 6; ++a) av[a] = Am[ri[a]*LDA + k];
#pragma unroll
        for (int c = 0; c < 6; ++c) bv[c] = Bm[k*LDA + ci[c]];
#pragma unroll
        for (int a = 0; a < 6; ++a)
#pragma unroll
            for (int c = 0; c < 6; ++c)
                R[a*6+c] = fmaf(av[a], bv[c], R[a*6+c]);
    }
}

__device__ __forceinline__ void st84(float* __restrict__ Dm,
                                     const float* __restrict__ R,
                                     const int* ri, const int* ci,
                                     const bool* rv, const bool* cv)
{
#pragma unroll
    for (int a = 0; a < 6; ++a) if (rv[a]) {
#pragma unroll
        for (int c = 0; c < 6; ++c) if (cv[c])
            Dm[ri[a]*LDA + ci[c]] = R[a*6+c];
    }
}

// ---------------- precompute: U76 [76][128], c [128] -----------------------
// z' = z*Pstep + qstep per RK4 step (affine since f is affine).
// Pstep = I + h*Wt + h^2/2 Wt^2 + h^3/6 Wt^3 + h^4/24 Wt^4  (Wt = W^T)
// (P,q)^2 = (P*P, q*P + q);  A20 = A16 then A4:  P20 = P16*P4, q20 = q16*P4 + q4
// U = (P20 + I) * Wpen^T  (keep rows 0..75), c = q20*Wpen^T + bpen
__global__ __launch_bounds__(256) void precomp_kernel(
    const float* __restrict__ W,     // [84][84]
    const float* __restrict__ b,     // [84]
    const float* __restrict__ Wpen,  // [128][84]
    const float* __restrict__ bpen,  // [128]
    float* __restrict__ U_out,       // [76][128]
    float* __restrict__ c_out)       // [128]
{
    __shared__ float A[DD*LDA];
    __shared__ float B[DD*LDA];
    __shared__ float qa[DD], qb[DD], qacc[DD], qcur[DD], qtmp[DD], q4s[DD];

    const int tid = threadIdx.x;
    const int tr = tid >> 4, tc = tid & 15;
    int ri[6], ci[6]; bool rv[6], cv[6];
#pragma unroll
    for (int a = 0; a < 6; ++a) {
        int i = tr + 16*a; rv[a] = (i < DD); ri[a] = rv[a] ? i : 0;
        int j = tc + 16*a; cv[a] = (j < DD); ci[a] = cv[a] ? j : 0;
    }

    // stage Wt into A and B: Wt[c][r] = W[r][c]
    for (int idx = tid; idx < DD*DD; idx += 256) {
        int r = idx / DD, c = idx % DD;
        float w = W[idx];
        A[c*LDA + r] = w;
        B[c*LDA + r] = w;
    }
    if (tid < DD) { qa[tid] = b[tid]; qacc[tid] = b[tid]; }
    __syncthreads();

    // ---- q chain while A = Wt ----
    // q2 = (h/2) q1*Wt + b
    if (tid < DD) { float s = 0.f;
        for (int k = 0; k < DD; ++k) s = fmaf(qa[k], A[k*LDA+tid], s);
        qb[tid] = 0.5f*HSTEP*s + b[tid]; }
    __syncthreads();
    if (tid < DD) qacc[tid] += 2.f*qb[tid];
    __syncthreads();
    // q3 = (h/2) q2*Wt + b
    if (tid < DD) { float s = 0.f;
        for (int k = 0; k < DD; ++k) s = fmaf(qb[k], A[k*LDA+tid], s);
        qa[tid] = 0.5f*HSTEP*s + b[tid]; }
    __syncthreads();
    if (tid < DD) qacc[tid] += 2.f*qa[tid];
    __syncthreads();
    // q4 = h q3*Wt + b
    if (tid < DD) { float s = 0.f;
        for (int k = 0; k < DD; ++k) s = fmaf(qa[k], A[k*LDA+tid], s);
        qb[tid] = HSTEP*s + b[tid]; }
    __syncthreads();
    if (tid < DD) qcur[tid] = (HSTEP/6.f)*(qacc[tid] + qb[tid]);  // qstep
    __syncthreads();

    // ---- build Pstep via Taylor terms ----
    float R[36], Pacc[36], P4s[36];
#pragma unroll
    for (int a = 0; a < 6; ++a)
#pragma unroll
        for (int c = 0; c < 6; ++c)
            Pacc[a*6+c] = ((ri[a] == ci[c]) ? 1.f : 0.f) + HSTEP*A[ri[a]*LDA + ci[c]];

    mm84(A, B, ri, ci, R);                     // Wt^2
#pragma unroll
    for (int i = 0; i < 36; ++i) Pacc[i] = fmaf(0.5f*HSTEP*HSTEP, R[i], Pacc[i]);
    __syncthreads();
    st84(A, R, ri, ci, rv, cv);                // A = Wt^2
    __syncthreads();

    mm84(A, B, ri, ci, R);                     // Wt^3
    {   const float c3 = HSTEP*HSTEP*HSTEP/6.f;
#pragma unroll
        for (int i = 0; i < 36; ++i) Pacc[i] = fmaf(c3, R[i], Pacc[i]); }
    __syncthreads();
    st84(A, R, ri, ci, rv, cv);                // A = Wt^3
    __syncthreads();

    mm84(A, B, ri, ci, R);                     // Wt^4
    {   const float c4 = HSTEP*HSTEP*HSTEP*HSTEP/24.f;
#pragma unroll
        for (int i = 0; i < 36; ++i) Pacc[i] = fmaf(c4, R[i], Pacc[i]); }
    __syncthreads();
    st84(A, Pacc, ri, ci, rv, cv);             // A = B = Pstep
    st84(B, Pacc, ri, ci, rv, cv);
    __syncthreads();

    // ---- 4 affine squarings: Pstep -> P2 -> P4 -> P8 -> P16 ----
    for (int s = 0; s < 4; ++s) {
        if (tid < DD) { float t2 = 0.f;
            for (int k = 0; k < DD; ++k) t2 = fmaf(qcur[k], A[k*LDA+tid], t2);
            qtmp[tid] = t2 + qcur[tid]; }
        mm84(A, B, ri, ci, R);
        __syncthreads();
        st84(A, R, ri, ci, rv, cv);
        st84(B, R, ri, ci, rv, cv);
        if (tid < DD) qcur[tid] = qtmp[tid];
        if (s == 1) {                           // save (P4, q4)
#pragma unroll
            for (int i = 0; i < 36; ++i) P4s[i] = R[i];
            if (tid < DD) q4s[tid] = qtmp[tid];
        }
        __syncthreads();
    }

    // ---- compose A20 = A16 then A4 ----
    st84(B, P4s, ri, ci, rv, cv);               // B = P4
    __syncthreads();
    if (tid < DD) { float t2 = 0.f;
        for (int k = 0; k < DD; ++k) t2 = fmaf(qcur[k], B[k*LDA+tid], t2);
        qtmp[tid] = t2 + q4s[tid]; }
    mm84(A, B, ri, ci, R);                      // P20 = P16*P4
    __syncthreads();
    st84(A, R, ri, ci, rv, cv);                 // A = P20
    if (tid < DD) qcur[tid] = qtmp[tid];        // q20
    __syncthreads();

    // ---- fold with Wpen: U[k][j] = Wpen[j][k] + sum_m P20[k][m]*Wpen[j][m] ----
    for (int o = tid; o < K_IN*HCH; o += 256) {
        const int k = o >> 7, j = o & 127;
        const float* wr = &Wpen[j*DD];
        float acc = wr[k];                      // identity term
        for (int m = 0; m < DD; ++m) acc = fmaf(A[k*LDA+m], wr[m], acc);
        U_out[o] = acc;
    }
    if (tid < HCH) {
        const float* wr = &Wpen[tid*DD];
        float acc = bpen[tid];
        for (int m = 0; m < DD; ++m) acc = fmaf(qcur[m], wr[m], acc);
        c_out[tid] = acc;
    }
}

// ---------------- main fused kernel ----------------------------------------
// out[t] = relu(x[t] * U76 + c) * Wfin^T + bfin
// 512 blocks x 256 threads; 128 tokens/block, j-dim split in two halves.
__global__ __launch_bounds__(256) void main_kernel(
    const float* __restrict__ x,     // [65536][76]
    const float* __restrict__ Ug,    // [76][128]
    const float* __restrict__ cg,    // [128]
    const float* __restrict__ Wfin,  // [5][128]
    const float* __restrict__ bfin,  // [5]
    float* __restrict__ out)         // [65536][5]
{
    __shared__ float Ul[K_IN*HCH];   // 38.9 KB
    __shared__ float cl[HCH];
    __shared__ float Vl[CCH*HCH];
    __shared__ float op[256*CCH];

    const int tid = threadIdx.x;
    for (int i = tid; i < (K_IN*HCH)/4; i += 256)
        ((float4*)Ul)[i] = ((const float4*)Ug)[i];
    if (tid < HCH) cl[tid] = cg[tid];
    for (int i = tid; i < CCH*HCH; i += 256) Vl[i] = Wfin[i];
    __syncthreads();

    const int tl = tid & 127;
    const int jh = tid >> 7;                        // which j-half
    const size_t t = (size_t)blockIdx.x * 128 + tl; // token
    const float4* __restrict__ xp = (const float4*)(x + t*K_IN);
    float4 xv[19];
#pragma unroll
    for (int i = 0; i < 19; ++i) xv[i] = xp[i];

    float oa[CCH];
#pragma unroll
    for (int m = 0; m < CCH; ++m) oa[m] = 0.f;

    for (int jc = 0; jc < 8; ++jc) {
        const int j0 = (jh*8 + jc)*8;
        float4 h0 = *(const float4*)&cl[j0];
        float4 h1 = *(const float4*)&cl[j0+4];
#pragma unroll
        for (int kq = 0; kq < 19; ++kq) {
            const float4 xq = xv[kq];
#pragma unroll
            for (int dk = 0; dk < 4; ++dk) {
                const int k = kq*4 + dk;
                const float4 u0 = *(const float4*)&Ul[k*HCH + j0];
                const float4 u1 = *(const float4*)&Ul[k*HCH + j0 + 4];
                const float xs = (dk == 0) ? xq.x : (dk == 1) ? xq.y
                               : (dk == 2) ? xq.z : xq.w;
                h0.x = fmaf(xs, u0.x, h0.x); h0.y = fmaf(xs, u0.y, h0.y);
                h0.z = fmaf(xs, u0.z, h0.z); h0.w = fmaf(xs, u0.w, h0.w);
                h1.x = fmaf(xs, u1.x, h1.x); h1.y = fmaf(xs, u1.y, h1.y);
                h1.z = fmaf(xs, u1.z, h1.z); h1.w = fmaf(xs, u1.w, h1.w);
            }
        }
        // relu
        h0.x = fmaxf(h0.x, 0.f); h0.y = fmaxf(h0.y, 0.f);
        h0.z = fmaxf(h0.z, 0.f); h0.w = fmaxf(h0.w, 0.f);
        h1.x = fmaxf(h1.x, 0.f); h1.y = fmaxf(h1.y, 0.f);
        h1.z = fmaxf(h1.z, 0.f); h1.w = fmaxf(h1.w, 0.f);
        // final 128x5 matmul (partial over this thread's j-range)
#pragma unroll
        for (int m = 0; m < CCH; ++m) {
            const float4 v0 = *(const float4*)&Vl[m*HCH + j0];
            const float4 v1 = *(const float4*)&Vl[m*HCH + j0 + 4];
            oa[m] += h0.x*v0.x + h0.y*v0.y + h0.z*v0.z + h0.w*v0.w
                   + h1.x*v1.x + h1.y*v1.y + h1.z*v1.z + h1.w*v1.w;
        }
    }

#pragma unroll
    for (int m = 0; m < CCH; ++m) op[tid*CCH + m] = oa[m];
    __syncthreads();
    if (tid < 128) {
        const size_t tt = (size_t)blockIdx.x*128 + tid;
#pragma unroll
        for (int m = 0; m < CCH; ++m)
            out[tt*CCH + m] = op[tid*CCH + m] + op[(tid+128)*CCH + m] + bfin[m];
    }
}

extern "C" void kernel_launch(void* const* d_in, const int* in_sizes, int n_in,
                              void* d_out, int out_size, void* d_ws, size_t ws_size,
                              hipStream_t stream)
{
    const float* x    = (const float*)d_in[0];
    const float* Wode = (const float*)d_in[1];
    const float* bode = (const float*)d_in[2];
    const float* Wpen = (const float*)d_in[3];
    const float* bpen = (const float*)d_in[4];
    const float* Wfin = (const float*)d_in[5];
    const float* bfin = (const float*)d_in[6];
    float* out = (float*)d_out;

    float* U = (float*)d_ws;            // 76*128 floats
    float* c = U + K_IN*HCH;            // 128 floats

    precomp_kernel<<<dim3(1), dim3(256), 0, stream>>>(Wode, bode, Wpen, bpen, U, c);
    main_kernel<<<dim3(512), dim3(256), 0, stream>>>(x, U, c, Wfin, bfin, out);
}

// Round 2
// 112.878 us; speedup vs baseline: 1.2812x; 1.2812x over previous
//
#include <hip/hip_runtime.h>

#define K_IN 76      // input feature dim
#define DD 84        // augmented dim
#define HCH 128      // penultimate width
#define CCH 5        // classes
#define HSTEP 0.05f  // 1/20

#define LA 88        // row-major matrix stride (16B-aligned rows, 2-way LDS conflicts max)
#define LB 92        // transposed-copy stride (16B-aligned rows, 2-way conflicts max)
#define LC 85        // fold chunk stride (odd -> conflict-free scalar column reads)

// Quartic Taylor factorization: 1+x+x^2/2+x^3/6+x^4/24 = (x^2+a1*x+b1)(x^2+a2*x+b2)/24
// a1+a2=4 and b1*b2=24 hold exactly (in double); residual coeff error ~1e-5.
constexpr double A1D = 3.4588904;
constexpr double B1D = 3.7812572;
constexpr double A2D = 4.0 - A1D;
constexpr double B2D = 24.0 / B1D;

// ---- 84x84x84 matmul: C[i][j] = sum_k A[i][k] * Bt[j][k], 4x7 tile/thread ----
// Thread grid 21x12 (252 of 256 threads). rows: tr + 21*a, cols: tc*7 + c.
__device__ __forceinline__ void mm84(const float* __restrict__ Am,
                                     const float* __restrict__ Btm,
                                     int tr, int tc, float* __restrict__ R)
{
#pragma unroll
    for (int i = 0; i < 28; ++i) R[i] = 0.f;
    for (int kg = 0; kg < 21; ++kg) {
        float4 av[4], bv[7];
#pragma unroll
        for (int a = 0; a < 4; ++a)
            av[a] = *(const float4*)&Am[(tr + 21*a)*LA + kg*4];
#pragma unroll
        for (int c = 0; c < 7; ++c)
            bv[c] = *(const float4*)&Btm[(tc*7 + c)*LB + kg*4];
#pragma unroll
        for (int a = 0; a < 4; ++a)
#pragma unroll
            for (int c = 0; c < 7; ++c) {
                float s = R[a*7+c];
                s = fmaf(av[a].x, bv[c].x, s);
                s = fmaf(av[a].y, bv[c].y, s);
                s = fmaf(av[a].z, bv[c].z, s);
                s = fmaf(av[a].w, bv[c].w, s);
                R[a*7+c] = s;
            }
    }
}

// ---------------- precompute: U76 [76][128], c [128] -----------------------
__global__ __launch_bounds__(256) void precomp_kernel(
    const float* __restrict__ W,     // [84][84]
    const float* __restrict__ b,     // [84]
    const float* __restrict__ Wpen,  // [128][84]
    const float* __restrict__ bpen,  // [128]
    float* __restrict__ U_out,       // [76][128]
    float* __restrict__ c_out)       // [128]
{
    __shared__ float A [DD*LA];          // row-major current matrix
    __shared__ float Bt[DD*LB];          // transposed copy (also fold chunk buffer)
    __shared__ float qa[DD], qb[DD], qacc[DD], qcur[DD], qtmp[DD], q4s[DD];

    const int tid = threadIdx.x;
    const bool act = tid < 252;
    const int tr = tid / 12, tc = tid % 12;

    // ---- stage M = h*W^T: A[i][j] = h*W[j][i]; Bt[j][i] = M[i][j] = h*W[j][i]
    for (int e = tid; e < DD*DD; e += 256) {
        int r = e / DD, c = e - r*DD;
        float w = HSTEP * W[e];
        A [c*LA + r] = w;
        Bt[r*LB + c] = w;
    }
    if (tid < DD) { qa[tid] = b[tid]; qacc[tid] = b[tid]; }
    __syncthreads();

    // ---- per-step affine constant q_step (A = M) ----
    // q2 = 0.5*(q1*M) + b
    if (tid < DD) { float s = 0.f;
        for (int k = 0; k < DD; ++k) s = fmaf(qa[k], A[k*LA + tid], s);
        qb[tid] = 0.5f*s + b[tid]; }
    __syncthreads();
    // q3 = 0.5*(q2*M) + b ; qacc += 2*q2
    if (tid < DD) { qacc[tid] += 2.f*qb[tid];
        float s = 0.f;
        for (int k = 0; k < DD; ++k) s = fmaf(qb[k], A[k*LA + tid], s);
        qa[tid] = 0.5f*s + b[tid]; }
    __syncthreads();
    // q4 = q3*M + b ; q_step = (h/6)(q1+2q2+2q3+q4)
    if (tid < DD) { qacc[tid] += 2.f*qa[tid];
        float s = 0.f;
        for (int k = 0; k < DD; ++k) s = fmaf(qa[k], A[k*LA + tid], s);
        float q4v = s + b[tid];
        qcur[tid] = (HSTEP/6.f)*(qacc[tid] + q4v); }

    float R[28], P4s[28];

    // ---- mm1: M2 = M*M; then Q1 -> A, Q2^T -> Bt ----
    float Mv[28];
    if (act) {
        mm84(A, Bt, tr, tc, R);
#pragma unroll
        for (int a = 0; a < 4; ++a)
#pragma unroll
            for (int c = 0; c < 7; ++c)
                Mv[a*7+c] = A[(tr + 21*a)*LA + (tc*7 + c)];
    }
    __syncthreads();
    if (act) {
        const float a1 = (float)A1D, b1 = (float)B1D;
        const float a2 = (float)A2D, b2 = (float)B2D;
#pragma unroll
        for (int a = 0; a < 4; ++a)
#pragma unroll
            for (int c = 0; c < 7; ++c) {
                int i = tr + 21*a, j = tc*7 + c;
                float d = (i == j) ? 1.f : 0.f;
                float m2 = R[a*7+c], mv = Mv[a*7+c];
                A [i*LA + j] = m2 + a1*mv + b1*d;
                Bt[j*LB + i] = m2 + a2*mv + b2*d;
            }
    }
    __syncthreads();

    // ---- mm2: Pstep = Q1*Q2 / 24 ----
    if (act) mm84(A, Bt, tr, tc, R);
    __syncthreads();
    if (act) {
#pragma unroll
        for (int a = 0; a < 4; ++a)
#pragma unroll
            for (int c = 0; c < 7; ++c) {
                int i = tr + 21*a, j = tc*7 + c;
                float v = R[a*7+c] * (1.f/24.f);
                A [i*LA + j] = v;
                Bt[j*LB + i] = v;
            }
    }
    __syncthreads();

    // ---- 4 affine squarings: (P,q) -> (P^2, q*P + q); save (P4,q4) at s==1 ----
    for (int s = 0; s < 4; ++s) {
        if (tid < DD) { float t2 = 0.f;
            for (int k = 0; k < DD; ++k) t2 = fmaf(qcur[k], A[k*LA + tid], t2);
            qtmp[tid] = t2 + qcur[tid]; }
        if (act) mm84(A, Bt, tr, tc, R);
        __syncthreads();
        if (act) {
#pragma unroll
            for (int a = 0; a < 4; ++a)
#pragma unroll
                for (int c = 0; c < 7; ++c) {
                    int i = tr + 21*a, j = tc*7 + c;
                    float v = R[a*7+c];
                    A [i*LA + j] = v;
                    Bt[j*LB + i] = v;
                }
        }
        if (tid < DD) qcur[tid] = qtmp[tid];
        if (s == 1) {
#pragma unroll
            for (int i = 0; i < 28; ++i) P4s[i] = R[i];
            if (tid < DD) q4s[tid] = qtmp[tid];
        }
        __syncthreads();
    }

    // ---- compose: P20 = P16*P4, q20 = q16*P4 + q4 ----
    if (act) {
#pragma unroll
        for (int a = 0; a < 4; ++a)
#pragma unroll
            for (int c = 0; c < 7; ++c)
                Bt[(tc*7 + c)*LB + (tr + 21*a)] = P4s[a*7+c];  // Bt = P4^T
    }
    __syncthreads();
    if (tid < DD) { float t2 = 0.f;
        for (int k = 0; k < DD; ++k) t2 = fmaf(qcur[k], Bt[tid*LB + k], t2);
        qtmp[tid] = t2 + q4s[tid]; }
    if (act) mm84(A, Bt, tr, tc, R);
    __syncthreads();
    if (act) {
#pragma unroll
        for (int a = 0; a < 4; ++a)
#pragma unroll
            for (int c = 0; c < 7; ++c)
                A[(tr + 21*a)*LA + (tc*7 + c)] = R[a*7+c];     // A = P20
    }
    if (tid < DD) qcur[tid] = qtmp[tid];                        // q20
    __syncthreads();

    // ---- fold: U[k][j] = Wpen[j][k] + sum_m P20[k][m]*Wpen[j][m]; 2 chunks of 64 j
    const int w = tid >> 6, l = tid & 63;
    for (int ch = 0; ch < 2; ++ch) {
        __syncthreads();
        // coalesced stage of Wpen rows [ch*64, ch*64+64) into Bt area, stride LC
        for (int e = tid; e < 64*DD; e += 256) {
            int lr = e / DD, m = e - lr*DD;
            Bt[lr*LC + m] = Wpen[ch*(64*DD) + e];
        }
        __syncthreads();
        float wp[DD];
#pragma unroll
        for (int m = 0; m < DD; ++m) wp[m] = Bt[l*LC + m];
        for (int it = 0; it < 19; ++it) {
            int k = w*19 + it;
            float acc = Bt[l*LC + k];          // identity term Wpen[j][k]
#pragma unroll
            for (int mg = 0; mg < 21; ++mg) {
                float4 a4 = *(const float4*)&A[k*LA + mg*4];   // broadcast
                acc = fmaf(a4.x, wp[4*mg+0], acc);
                acc = fmaf(a4.y, wp[4*mg+1], acc);
                acc = fmaf(a4.z, wp[4*mg+2], acc);
                acc = fmaf(a4.w, wp[4*mg+3], acc);
            }
            U_out[k*HCH + ch*64 + l] = acc;
        }
        if (w == 0) {
            float cc = bpen[ch*64 + l];
#pragma unroll
            for (int m = 0; m < DD; ++m) cc = fmaf(qcur[m], wp[m], cc);
            c_out[ch*64 + l] = cc;
        }
    }
}

// ---------------- main fused kernel (unchanged, passed round 1) ------------
__global__ __launch_bounds__(256) void main_kernel(
    const float* __restrict__ x,     // [65536][76]
    const float* __restrict__ Ug,    // [76][128]
    const float* __restrict__ cg,    // [128]
    const float* __restrict__ Wfin,  // [5][128]
    const float* __restrict__ bfin,  // [5]
    float* __restrict__ out)         // [65536][5]
{
    __shared__ float Ul[K_IN*HCH];
    __shared__ float cl[HCH];
    __shared__ float Vl[CCH*HCH];
    __shared__ float op[256*CCH];

    const int tid = threadIdx.x;
    for (int i = tid; i < (K_IN*HCH)/4; i += 256)
        ((float4*)Ul)[i] = ((const float4*)Ug)[i];
    if (tid < HCH) cl[tid] = cg[tid];
    for (int i = tid; i < CCH*HCH; i += 256) Vl[i] = Wfin[i];
    __syncthreads();

    const int tl = tid & 127;
    const int jh = tid >> 7;
    const size_t t = (size_t)blockIdx.x * 128 + tl;
    const float4* __restrict__ xp = (const float4*)(x + t*K_IN);
    float4 xv[19];
#pragma unroll
    for (int i = 0; i < 19; ++i) xv[i] = xp[i];

    float oa[CCH];
#pragma unroll
    for (int m = 0; m < CCH; ++m) oa[m] = 0.f;

    for (int jc = 0; jc < 8; ++jc) {
        const int j0 = (jh*8 + jc)*8;
        float4 h0 = *(const float4*)&cl[j0];
        float4 h1 = *(const float4*)&cl[j0+4];
#pragma unroll
        for (int kq = 0; kq < 19; ++kq) {
            const float4 xq = xv[kq];
#pragma unroll
            for (int dk = 0; dk < 4; ++dk) {
                const int k = kq*4 + dk;
                const float4 u0 = *(const float4*)&Ul[k*HCH + j0];
                const float4 u1 = *(const float4*)&Ul[k*HCH + j0 + 4];
                const float xs = (dk == 0) ? xq.x : (dk == 1) ? xq.y
                               : (dk == 2) ? xq.z : xq.w;
                h0.x = fmaf(xs, u0.x, h0.x); h0.y = fmaf(xs, u0.y, h0.y);
                h0.z = fmaf(xs, u0.z, h0.z); h0.w = fmaf(xs, u0.w, h0.w);
                h1.x = fmaf(xs, u1.x, h1.x); h1.y = fmaf(xs, u1.y, h1.y);
                h1.z = fmaf(xs, u1.z, h1.z); h1.w = fmaf(xs, u1.w, h1.w);
            }
        }
        h0.x = fmaxf(h0.x, 0.f); h0.y = fmaxf(h0.y, 0.f);
        h0.z = fmaxf(h0.z, 0.f); h0.w = fmaxf(h0.w, 0.f);
        h1.x = fmaxf(h1.x, 0.f); h1.y = fmaxf(h1.y, 0.f);
        h1.z = fmaxf(h1.z, 0.f); h1.w = fmaxf(h1.w, 0.f);
#pragma unroll
        for (int m = 0; m < CCH; ++m) {
            const float4 v0 = *(const float4*)&Vl[m*HCH + j0];
            const float4 v1 = *(const float4*)&Vl[m*HCH + j0 + 4];
            oa[m] += h0.x*v0.x + h0.y*v0.y + h0.z*v0.z + h0.w*v0.w
                   + h1.x*v1.x + h1.y*v1.y + h1.z*v1.z + h1.w*v1.w;
        }
    }

#pragma unroll
    for (int m = 0; m < CCH; ++m) op[tid*CCH + m] = oa[m];
    __syncthreads();
    if (tid < 128) {
        const size_t tt = (size_t)blockIdx.x*128 + tid;
#pragma unroll
        for (int m = 0; m < CCH; ++m)
            out[tt*CCH + m] = op[tid*CCH + m] + op[(tid+128)*CCH + m] + bfin[m];
    }
}

extern "C" void kernel_launch(void* const* d_in, const int* in_sizes, int n_in,
                              void* d_out, int out_size, void* d_ws, size_t ws_size,
                              hipStream_t stream)
{
    const float* x    = (const float*)d_in[0];
    const float* Wode = (const float*)d_in[1];
    const float* bode = (const float*)d_in[2];
    const float* Wpen = (const float*)d_in[3];
    const float* bpen = (const float*)d_in[4];
    const float* Wfin = (const float*)d_in[5];
    const float* bfin = (const float*)d_in[6];
    float* out = (float*)d_out;

    float* U = (float*)d_ws;            // 76*128 floats
    float* c = U + K_IN*HCH;            // 128 floats

    precomp_kernel<<<dim3(1), dim3(256), 0, stream>>>(Wode, bode, Wpen, bpen, U, c);
    main_kernel<<<dim3(512), dim3(256), 0, stream>>>(x, U, c, Wfin, bfin, out);
}

// Round 3
// 82.183 us; speedup vs baseline: 1.7598x; 1.3735x over previous
//
#include <hip/hip_runtime.h>

#define K_IN 76      // input feature dim
#define DD 84        // augmented dim
#define HCH 128      // penultimate width
#define CCH 5        // classes

#define LDK 88       // LDS row stride, A operand (16B-aligned, <=2-way conflicts)
#define LBS 92       // LDS row stride, B columns (16B-aligned, <=2-way conflicts)
#define LC  85       // fold Wpen chunk stride

// ws float offsets (all 16B-aligned)
#define OFF_K   0        // K = W^T           [84][84]
#define OFF_K2  7056     // K^2
#define OFF_K3  14112    // K^3
#define OFF_K4  21168    // K^4
#define OFF_H2  28224    // Horner intermediate
#define OFF_E   35280    // exp(K)
#define OFF_QV  42336    // qv = b*phi1(K)    [84]
#define OFF_U   43008    // U                 [76][128]
#define OFF_C   52736    // c                 [128]

// phi1 Taylor coeffs: 1/(k+1)!
__device__ __constant__ float PHC[13] = {
    1.f, 0.5f, 1.f/6.f, 1.f/24.f, 1.f/120.f, 1.f/720.f, 1.f/5040.f,
    1.f/40320.f, 1.f/362880.f, 1.f/3628800.f, 1.f/39916800.f,
    1.f/479001600.f, 1.f/6227020800.f };

// ---------------- small-matmul uber kernel ---------------------------------
// exp(K) via degree-12 Taylor, Paterson-Stockmeyer (B = K^4):
//   C0 = I + K + K2/2 + K3/6
//   C1 = I/24 + K/120 + K2/720 + K3/5040
//   C2 = I/40320 + K/362880 + K2/3628800 + K3/39916800
//   H1 = K4/12! + C2        (elementwise)
//   H2 = H1*K4 + C1         (matmul, mode 2)
//   E  = H2*K4 + C0         (matmul, mode 3)
// mode 0 (8 blocks):  blk0-6: K2 = K*K (blk0 also dumps K to ws); blk7: qv
// mode 1 (14 blocks): blk0-6: K3 = K2*K; blk7-13: K4 = K2*K2
// mode 2 (7 blocks):  H2
// mode 3 (7 blocks):  E
__global__ __launch_bounds__(256) void mm_kernel(
    int mode, const float* __restrict__ W, const float* __restrict__ bode,
    float* __restrict__ ws)
{
    __shared__ float As[DD*LDK];     // 29.6 KB
    __shared__ float Bs[12*LBS];     // 4.4 KB
    __shared__ float vcur[DD];

    const int tid = threadIdx.x;
    const int blk = blockIdx.x;

    // ---------- qv block (needs only K) ----------
    if (mode == 0 && blk == 7) {
        for (int e = tid; e < DD*DD; e += 256)
            As[(e % DD)*LDK + (e / DD)] = W[e];       // As = K = W^T
        float acc = 0.f;
        if (tid < DD) vcur[tid] = bode[tid];
        __syncthreads();
        if (tid < DD) acc = bode[tid];
        for (int k = 1; k <= 12; ++k) {
            float nv = 0.f;
            if (tid < DD)
                for (int i = 0; i < DD; ++i)
                    nv = fmaf(vcur[i], As[i*LDK + tid], nv);
            __syncthreads();
            if (tid < DD) { vcur[tid] = nv; acc = fmaf(nv, PHC[k], acc); }
            __syncthreads();
        }
        if (tid < DD) ws[OFF_QV + tid] = acc;
        return;
    }

    const int mmb = (mode == 1 && blk >= 7) ? blk - 7 : blk;
    const int j0 = mmb * 12;
    const bool b_is_K4sq = (mode == 1 && blk >= 7);   // K4 = K2*K2 path

    // ---------- stage A operand (84x84 -> As, row-major, stride LDK) ----------
    if (mode == 0) {
        // As = K (transpose of W): K[i][k] = W[k][i]
        for (int e = tid; e < DD*DD; e += 256)
            As[(e % DD)*LDK + (e / DD)] = W[e];
    } else if (mode == 1) {
        for (int e = tid; e < 1764; e += 256) {
            int r = e / 21, c = (e % 21)*4;
            *(float4*)&As[r*LDK + c] = *(const float4*)&ws[OFF_K2 + r*84 + c];
        }
    } else if (mode == 2) {
        // As = H1 = K4/12! + I/40320 + K/362880 + K2/3628800 + K3/39916800
        for (int e = tid; e < 1764; e += 256) {
            int r = e / 21, c = (e % 21)*4;
            float4 v4 = *(const float4*)&ws[OFF_K4 + r*84 + c];
            float4 vK = *(const float4*)&ws[OFF_K  + r*84 + c];
            float4 v2 = *(const float4*)&ws[OFF_K2 + r*84 + c];
            float4 v3 = *(const float4*)&ws[OFF_K3 + r*84 + c];
            float o[4] = {v4.x, v4.y, v4.z, v4.w};
            float k_[4] = {vK.x, vK.y, vK.z, vK.w};
            float t2[4] = {v2.x, v2.y, v2.z, v2.w};
            float t3[4] = {v3.x, v3.y, v3.z, v3.w};
#pragma unroll
            for (int q = 0; q < 4; ++q) {
                float d = (r == c + q) ? (1.f/40320.f) : 0.f;
                o[q] = o[q]*(1.f/479001600.f) + d + k_[q]*(1.f/362880.f)
                     + t2[q]*(1.f/3628800.f) + t3[q]*(1.f/39916800.f);
            }
            *(float4*)&As[r*LDK + c] = make_float4(o[0], o[1], o[2], o[3]);
        }
    } else {
        for (int e = tid; e < 1764; e += 256) {
            int r = e / 21, c = (e % 21)*4;
            *(float4*)&As[r*LDK + c] = *(const float4*)&ws[OFF_H2 + r*84 + c];
        }
    }

    // ---------- stage B columns j0..j0+11 -> Bs[j][k] ----------
    if (mode == 0 || (mode == 1 && !b_is_K4sq)) {
        // B = K: Bs[j][k] = K[k][j0+j] = W[(j0+j)*84 + k]  (coalesced rows of W)
        for (int e = tid; e < 252; e += 256) {
            int j = e / 21, c = (e % 21)*4;
            *(float4*)&Bs[j*LBS + c] = *(const float4*)&W[(j0 + j)*84 + c];
        }
    } else {
        const int srco = b_is_K4sq ? OFF_K2 : OFF_K4;   // modes 2,3 use K4
        for (int e = tid; e < 1008; e += 256) {
            int k = e / 12, j = e % 12;
            Bs[j*LBS + k] = ws[srco + k*84 + j0 + j];
        }
    }
    __syncthreads();

    // blk0 of mode0 dumps K (row-major) to ws for later stages
    if (mode == 0 && blk == 0) {
        for (int e = tid; e < DD*DD; e += 256)
            ws[OFF_K + e] = As[(e / DD)*LDK + (e % DD)];
    }

    // ---------- compute: 4 rows x 1 col per thread ----------
    const int tc = tid % 12, tr = tid / 12;
    if (tr >= 21) return;
    float R[4] = {0.f, 0.f, 0.f, 0.f};
    for (int kg = 0; kg < 21; ++kg) {
        float4 bv = *(const float4*)&Bs[tc*LBS + kg*4];
#pragma unroll
        for (int a = 0; a < 4; ++a) {
            float4 av = *(const float4*)&As[(tr + 21*a)*LDK + kg*4];
            R[a] = fmaf(av.x, bv.x, R[a]);
            R[a] = fmaf(av.y, bv.y, R[a]);
            R[a] = fmaf(av.z, bv.z, R[a]);
            R[a] = fmaf(av.w, bv.w, R[a]);
        }
    }

    // ---------- epilogue + write ----------
    const int j = j0 + tc;
#pragma unroll
    for (int a = 0; a < 4; ++a) {
        const int i = tr + 21*a;
        float v = R[a];
        if (mode == 0) {
            ws[OFF_K2 + i*84 + j] = v;
        } else if (mode == 1) {
            ws[(blk < 7 ? OFF_K3 : OFF_K4) + i*84 + j] = v;
        } else if (mode == 2) {
            v += ((i == j) ? (1.f/24.f) : 0.f)
               + ws[OFF_K  + i*84 + j]*(1.f/120.f)
               + ws[OFF_K2 + i*84 + j]*(1.f/720.f)
               + ws[OFF_K3 + i*84 + j]*(1.f/5040.f);
            ws[OFF_H2 + i*84 + j] = v;
        } else {
            v += ((i == j) ? 1.f : 0.f)
               + ws[OFF_K  + i*84 + j]
               + ws[OFF_K2 + i*84 + j]*0.5f
               + ws[OFF_K3 + i*84 + j]*(1.f/6.f);
            ws[OFF_E + i*84 + j] = v;
        }
    }
}

// ---------------- fold: U[k][j] = Wpen[j][k] + sum_m E[k][m]*Wpen[j][m] ----
__global__ __launch_bounds__(256) void fold_kernel(
    const float* __restrict__ Wpen, const float* __restrict__ bpen,
    float* __restrict__ ws)
{
    __shared__ float Af[DD*LDK];
    __shared__ float Wc[64*LC];

    const int tid = threadIdx.x;
    const int ch = blockIdx.x;
    for (int e = tid; e < 1764; e += 256) {
        int r = e / 21, c = (e % 21)*4;
        *(float4*)&Af[r*LDK + c] = *(const float4*)&ws[OFF_E + r*84 + c];
    }
    for (int e = tid; e < 64*DD; e += 256) {
        int lr = e / DD, m = e - lr*DD;
        Wc[lr*LC + m] = Wpen[ch*(64*DD) + e];
    }
    __syncthreads();

    const int w = tid >> 6, l = tid & 63;
    float wp[DD];
#pragma unroll
    for (int m = 0; m < DD; ++m) wp[m] = Wc[l*LC + m];
    for (int it = 0; it < 19; ++it) {
        const int k = w*19 + it;
        float acc = Wc[l*LC + k];               // identity term Wpen[j][k]
#pragma unroll
        for (int mg = 0; mg < 21; ++mg) {
            float4 a4 = *(const float4*)&Af[k*LDK + mg*4];   // broadcast
            acc = fmaf(a4.x, wp[4*mg+0], acc);
            acc = fmaf(a4.y, wp[4*mg+1], acc);
            acc = fmaf(a4.z, wp[4*mg+2], acc);
            acc = fmaf(a4.w, wp[4*mg+3], acc);
        }
        ws[OFF_U + k*HCH + ch*64 + l] = acc;
    }
    if (w == 0) {
        float cc = bpen[ch*64 + l];
#pragma unroll
        for (int m = 0; m < DD; ++m) cc = fmaf(ws[OFF_QV + m], wp[m], cc);
        ws[OFF_C + ch*64 + l] = cc;
    }
}

// ---------------- main fused kernel (unchanged, verified) ------------------
__global__ __launch_bounds__(256) void main_kernel(
    const float* __restrict__ x,     // [65536][76]
    const float* __restrict__ Ug,    // [76][128]
    const float* __restrict__ cg,    // [128]
    const float* __restrict__ Wfin,  // [5][128]
    const float* __restrict__ bfin,  // [5]
    float* __restrict__ out)         // [65536][5]
{
    __shared__ float Ul[K_IN*HCH];
    __shared__ float cl[HCH];
    __shared__ float Vl[CCH*HCH];
    __shared__ float op[256*CCH];

    const int tid = threadIdx.x;
    for (int i = tid; i < (K_IN*HCH)/4; i += 256)
        ((float4*)Ul)[i] = ((const float4*)Ug)[i];
    if (tid < HCH) cl[tid] = cg[tid];
    for (int i = tid; i < CCH*HCH; i += 256) Vl[i] = Wfin[i];
    __syncthreads();

    const int tl = tid & 127;
    const int jh = tid >> 7;
    const size_t t = (size_t)blockIdx.x * 128 + tl;
    const float4* __restrict__ xp = (const float4*)(x + t*K_IN);
    float4 xv[19];
#pragma unroll
    for (int i = 0; i < 19; ++i) xv[i] = xp[i];

    float oa[CCH];
#pragma unroll
    for (int m = 0; m < CCH; ++m) oa[m] = 0.f;

    for (int jc = 0; jc < 8; ++jc) {
        const int j0 = (jh*8 + jc)*8;
        float4 h0 = *(const float4*)&cl[j0];
        float4 h1 = *(const float4*)&cl[j0+4];
#pragma unroll
        for (int kq = 0; kq < 19; ++kq) {
            const float4 xq = xv[kq];
#pragma unroll
            for (int dk = 0; dk < 4; ++dk) {
                const int k = kq*4 + dk;
                const float4 u0 = *(const float4*)&Ul[k*HCH + j0];
                const float4 u1 = *(const float4*)&Ul[k*HCH + j0 + 4];
                const float xs = (dk == 0) ? xq.x : (dk == 1) ? xq.y
                               : (dk == 2) ? xq.z : xq.w;
                h0.x = fmaf(xs, u0.x, h0.x); h0.y = fmaf(xs, u0.y, h0.y);
                h0.z = fmaf(xs, u0.z, h0.z); h0.w = fmaf(xs, u0.w, h0.w);
                h1.x = fmaf(xs, u1.x, h1.x); h1.y = fmaf(xs, u1.y, h1.y);
                h1.z = fmaf(xs, u1.z, h1.z); h1.w = fmaf(xs, u1.w, h1.w);
            }
        }
        h0.x = fmaxf(h0.x, 0.f); h0.y = fmaxf(h0.y, 0.f);
        h0.z = fmaxf(h0.z, 0.f); h0.w = fmaxf(h0.w, 0.f);
        h1.x = fmaxf(h1.x, 0.f); h1.y = fmaxf(h1.y, 0.f);
        h1.z = fmaxf(h1.z, 0.f); h1.w = fmaxf(h1.w, 0.f);
#pragma unroll
        for (int m = 0; m < CCH; ++m) {
            const float4 v0 = *(const float4*)&Vl[m*HCH + j0];
            const float4 v1 = *(const float4*)&Vl[m*HCH + j0 + 4];
            oa[m] += h0.x*v0.x + h0.y*v0.y + h0.z*v0.z + h0.w*v0.w
                   + h1.x*v1.x + h1.y*v1.y + h1.z*v1.z + h1.w*v1.w;
        }
    }

#pragma unroll
    for (int m = 0; m < CCH; ++m) op[tid*CCH + m] = oa[m];
    __syncthreads();
    if (tid < 128) {
        const size_t tt = (size_t)blockIdx.x*128 + tid;
#pragma unroll
        for (int m = 0; m < CCH; ++m)
            out[tt*CCH + m] = op[tid*CCH + m] + op[(tid+128)*CCH + m] + bfin[m];
    }
}

extern "C" void kernel_launch(void* const* d_in, const int* in_sizes, int n_in,
                              void* d_out, int out_size, void* d_ws, size_t ws_size,
                              hipStream_t stream)
{
    const float* x    = (const float*)d_in[0];
    const float* Wode = (const float*)d_in[1];
    const float* bode = (const float*)d_in[2];
    const float* Wpen = (const float*)d_in[3];
    const float* bpen = (const float*)d_in[4];
    const float* Wfin = (const float*)d_in[5];
    const float* bfin = (const float*)d_in[6];
    float* out = (float*)d_out;
    float* wsf = (float*)d_ws;

    mm_kernel<<<dim3(8),  dim3(256), 0, stream>>>(0, Wode, bode, wsf);
    mm_kernel<<<dim3(14), dim3(256), 0, stream>>>(1, Wode, bode, wsf);
    mm_kernel<<<dim3(7),  dim3(256), 0, stream>>>(2, Wode, bode, wsf);
    mm_kernel<<<dim3(7),  dim3(256), 0, stream>>>(3, Wode, bode, wsf);
    fold_kernel<<<dim3(2), dim3(256), 0, stream>>>(Wpen, bpen, wsf);
    main_kernel<<<dim3(512), dim3(256), 0, stream>>>(x, wsf + OFF_U, wsf + OFF_C,
                                                     Wfin, bfin, out);
}

// Round 4
// 69.995 us; speedup vs baseline: 2.0662x; 1.1741x over previous
//
#include <hip/hip_runtime.h>

#define K_IN 76      // input feature dim
#define DD 84        // augmented dim
#define HCH 128      // penultimate width
#define CCH 5        // classes

#define LDK 100      // LDS row stride for A operands (16B-aligned, spread banks)
#define LBS 92       // LDS row stride for B columns
#define LC  85       // fold Wpen chunk stride

// ws float offsets
#define OFF_K    0       // K = W^T          [84][84]
#define OFF_K2   7056
#define OFF_K3   14112
#define OFF_K4   21168
#define OFF_E    28224   // exp(K) (deg-8 Taylor)
#define OFF_QV   35280   // qv = b*phi1(K)   [84]
#define OFF_U    35392   // U                [76][128]
#define OFF_C    45120   // c                [128]
#define OFF_CTRF 60928   // barrier counters (uint), memset to 0 each launch

#define NCHB 14          // chain kernel blocks

// phi1 Taylor coeffs: 1/(k+1)!
__device__ __constant__ float PHC[11] = {
    1.f, 0.5f, 1.f/6.f, 1.f/24.f, 1.f/120.f, 1.f/720.f, 1.f/5040.f,
    1.f/40320.f, 1.f/362880.f, 1.f/3628800.f, 1.f/39916800.f };

// device-scope global barrier (all NCHB blocks co-resident: 14 << 256 CUs)
__device__ __forceinline__ void gbar(unsigned* ctr, int idx)
{
    __syncthreads();
    if (threadIdx.x == 0) {
        __threadfence();
        __hip_atomic_fetch_add(&ctr[idx], 1u, __ATOMIC_RELEASE, __HIP_MEMORY_SCOPE_AGENT);
        while (__hip_atomic_load(&ctr[idx], __ATOMIC_ACQUIRE,
                                 __HIP_MEMORY_SCOPE_AGENT) < (unsigned)NCHB) {
            __builtin_amdgcn_s_sleep(2);
        }
    }
    __syncthreads();
}

// C[i][j0+tc] = sum_k As[i][k]*Bs[tc][k], i = tr+21a  (84x84x12 slice)
__device__ __forceinline__ void mmdot(const float* __restrict__ As,
                                      const float* __restrict__ Bs,
                                      int tr, int tc, float* __restrict__ R)
{
    R[0] = R[1] = R[2] = R[3] = 0.f;
    for (int kg = 0; kg < 21; ++kg) {
        float4 bv = *(const float4*)&Bs[tc*LBS + kg*4];
#pragma unroll
        for (int a = 0; a < 4; ++a) {
            float4 av = *(const float4*)&As[(tr + 21*a)*LDK + kg*4];
            R[a] = fmaf(av.x, bv.x, R[a]); R[a] = fmaf(av.y, bv.y, R[a]);
            R[a] = fmaf(av.z, bv.z, R[a]); R[a] = fmaf(av.w, bv.w, R[a]);
        }
    }
}

// ---------------- fused precompute chain (one dispatch, 14 blocks) ---------
// exp(K), deg-8 Taylor, Paterson-Stockmeyer:
//   E = [I + K + K2/2 + K3/6] + [I/24 + K/120 + K2/720 + K3/5040 + K4/40320]*K4
// stage A: K2 (blk0-6; blk0 dumps K)      | barrier
// stage B: K3 (blk0-6), K4 (blk7-13)      | barrier
// stage C: E  (blk0-6), qv (blk7)         | barrier
// stage D: fold -> U, c (blk0-1)
__global__ __launch_bounds__(256) void chain_kernel(
    const float* __restrict__ W, const float* __restrict__ bode,
    const float* __restrict__ Wpen, const float* __restrict__ bpen,
    float* __restrict__ ws, unsigned* __restrict__ ctr)
{
    __shared__ float As[DD*LDK];
    __shared__ float Bs[12*LBS];
    __shared__ float Wc[64*LC];
    __shared__ float vcur[DD];

    const int tid = threadIdx.x;
    const int blk = blockIdx.x;
    const int tc = tid % 12, tr = tid / 12;
    const bool act = (tr < 21);
    float R[4];

    // ================= stage A =================
    if (blk < 7) {
        for (int e = tid; e < DD*DD; e += 256) {        // As = K = W^T
            int r = e / DD, c = e - r*DD;
            As[c*LDK + r] = W[e];
        }
        __syncthreads();
        if (blk == 0) {
            for (int e = tid; e < DD*DD; e += 256)      // dump K row-major
                ws[OFF_K + e] = As[(e/DD)*LDK + (e%DD)];
        }
        const int j0 = blk*12;
        for (int e = tid; e < 252; e += 256) {          // Bs[j][k] = K[k][j0+j]
            int j = e / 21, c4 = (e % 21)*4;
            *(float4*)&Bs[j*LBS + c4] = *(const float4*)&W[(j0+j)*84 + c4];
        }
        __syncthreads();
        if (act) {
            mmdot(As, Bs, tr, tc, R);
#pragma unroll
            for (int a = 0; a < 4; ++a)
                ws[OFF_K2 + (tr+21*a)*84 + j0 + tc] = R[a];
        }
    }
    gbar(ctr, 0);

    // ================= stage B =================
    {
        for (int e = tid; e < 1764; e += 256) {         // As = K2
            int r = e / 21, c4 = (e % 21)*4;
            *(float4*)&As[r*LDK + c4] = *(const float4*)&ws[OFF_K2 + r*84 + c4];
        }
        if (blk < 7) {
            const int j0 = blk*12;
            for (int e = tid; e < 252; e += 256) {      // Bs = K cols
                int j = e / 21, c4 = (e % 21)*4;
                *(float4*)&Bs[j*LBS + c4] = *(const float4*)&W[(j0+j)*84 + c4];
            }
            __syncthreads();
            if (act) {
                mmdot(As, Bs, tr, tc, R);
#pragma unroll
                for (int a = 0; a < 4; ++a)
                    ws[OFF_K3 + (tr+21*a)*84 + j0 + tc] = R[a];
            }
        } else {
            const int j0 = (blk-7)*12;
            for (int e = tid; e < 1008; e += 256) {     // Bs[j][k] = K2[k][j0+j]
                int k = e / 12, j = e % 12;
                Bs[j*LBS + k] = ws[OFF_K2 + k*84 + j0 + j];
            }
            __syncthreads();
            if (act) {
                mmdot(As, Bs, tr, tc, R);
#pragma unroll
                for (int a = 0; a < 4; ++a)
                    ws[OFF_K4 + (tr+21*a)*84 + j0 + tc] = R[a];
            }
        }
    }
    gbar(ctr, 1);

    // ================= stage C =================
    if (blk < 7) {
        // As = I/24 + K/120 + K2/720 + K3/5040 + K4/40320
        for (int e = tid; e < 1764; e += 256) {
            int r = e / 21, c4 = (e % 21)*4;
            float4 vK = *(const float4*)&ws[OFF_K  + r*84 + c4];
            float4 v2 = *(const float4*)&ws[OFF_K2 + r*84 + c4];
            float4 v3 = *(const float4*)&ws[OFF_K3 + r*84 + c4];
            float4 v4 = *(const float4*)&ws[OFF_K4 + r*84 + c4];
            float k_[4] = {vK.x, vK.y, vK.z, vK.w};
            float a2[4] = {v2.x, v2.y, v2.z, v2.w};
            float a3[4] = {v3.x, v3.y, v3.z, v3.w};
            float a4[4] = {v4.x, v4.y, v4.z, v4.w};
            float o[4];
#pragma unroll
            for (int q = 0; q < 4; ++q) {
                float d = (r == c4 + q) ? (1.f/24.f) : 0.f;
                o[q] = d + k_[q]*(1.f/120.f) + a2[q]*(1.f/720.f)
                     + a3[q]*(1.f/5040.f) + a4[q]*(1.f/40320.f);
            }
            *(float4*)&As[r*LDK + c4] = make_float4(o[0], o[1], o[2], o[3]);
        }
        const int j0 = blk*12;
        for (int e = tid; e < 1008; e += 256) {         // Bs[j][k] = K4[k][j0+j]
            int k = e / 12, j = e % 12;
            Bs[j*LBS + k] = ws[OFF_K4 + k*84 + j0 + j];
        }
        __syncthreads();
        if (act) {
            mmdot(As, Bs, tr, tc, R);
#pragma unroll
            for (int a = 0; a < 4; ++a) {
                const int i = tr + 21*a, j = j0 + tc;
                float v = R[a] + ((i == j) ? 1.f : 0.f)
                        + ws[OFF_K  + i*84 + j]
                        + ws[OFF_K2 + i*84 + j]*0.5f
                        + ws[OFF_K3 + i*84 + j]*(1.f/6.f);
                ws[OFF_E + i*84 + j] = v;
            }
        }
    } else if (blk == 7) {
        // qv = b * phi1(K), deg-10
        for (int e = tid; e < 1764; e += 256) {
            int r = e / 21, c4 = (e % 21)*4;
            *(float4*)&As[r*LDK + c4] = *(const float4*)&ws[OFF_K + r*84 + c4];
        }
        if (tid < DD) vcur[tid] = bode[tid];
        __syncthreads();
        float acc = (tid < DD) ? bode[tid] : 0.f;
        for (int kk = 1; kk <= 10; ++kk) {
            float nv = 0.f;
            if (tid < DD) {
                float s0 = 0.f, s1 = 0.f, s2 = 0.f, s3 = 0.f;
                for (int i = 0; i < DD; i += 4) {
                    s0 = fmaf(vcur[i+0], As[(i+0)*LDK + tid], s0);
                    s1 = fmaf(vcur[i+1], As[(i+1)*LDK + tid], s1);
                    s2 = fmaf(vcur[i+2], As[(i+2)*LDK + tid], s2);
                    s3 = fmaf(vcur[i+3], As[(i+3)*LDK + tid], s3);
                }
                nv = (s0 + s1) + (s2 + s3);
            }
            __syncthreads();
            if (tid < DD) { vcur[tid] = nv; acc = fmaf(nv, PHC[kk], acc); }
            __syncthreads();
        }
        if (tid < DD) ws[OFF_QV + tid] = acc;
    }
    gbar(ctr, 2);

    // ================= stage D: fold (blk 0,1) =================
    if (blk < 2) {
        for (int e = tid; e < 1764; e += 256) {         // As = E
            int r = e / 21, c4 = (e % 21)*4;
            *(float4*)&As[r*LDK + c4] = *(const float4*)&ws[OFF_E + r*84 + c4];
        }
        for (int e = tid; e < 64*DD; e += 256) {
            int lr = e / DD, m = e - lr*DD;
            Wc[lr*LC + m] = Wpen[blk*(64*DD) + e];
        }
        if (tid < DD) vcur[tid] = ws[OFF_QV + tid];
        __syncthreads();

        const int w = tid >> 6, l = tid & 63;
        float wp[DD];
#pragma unroll
        for (int m = 0; m < DD; ++m) wp[m] = Wc[l*LC + m];
        for (int it = 0; it < 19; ++it) {
            const int k = w*19 + it;
            float acc = Wc[l*LC + k];                   // identity term Wpen[j][k]
#pragma unroll
            for (int mg = 0; mg < 21; ++mg) {
                float4 a4 = *(const float4*)&As[k*LDK + mg*4];
                acc = fmaf(a4.x, wp[4*mg+0], acc);
                acc = fmaf(a4.y, wp[4*mg+1], acc);
                acc = fmaf(a4.z, wp[4*mg+2], acc);
                acc = fmaf(a4.w, wp[4*mg+3], acc);
            }
            ws[OFF_U + k*HCH + blk*64 + l] = acc;
        }
        if (w == 0) {
            float cc = bpen[blk*64 + l];
#pragma unroll
            for (int m = 0; m < DD; ++m) cc = fmaf(vcur[m], wp[m], cc);
            ws[OFF_C + blk*64 + l] = cc;
        }
    }
}

// ---------------- main fused kernel -----------------------------------------
// out[t] = relu(x[t]*U + c) * Wfin^T + bfin
// 512 blocks x 256 thr; block = 128 tokens; thread = 16 tokens x 4 j.
__global__ __launch_bounds__(256) void main_kernel(
    const float* __restrict__ x,     // [65536][76]
    const float* __restrict__ Ug,    // [76][128]
    const float* __restrict__ cg,    // [128]
    const float* __restrict__ Wfin,  // [5][128]
    const float* __restrict__ bfin,  // [5]
    float* __restrict__ out)         // [65536][5]
{
    __shared__ float Ut[K_IN*HCH];   // 38912 B ; reused as final out tile (640 f)
    __shared__ float xs[128*K_IN];   // 38912 B ; reused as opp[256*21]
    __shared__ float Vl[CCH*HCH];    // 2560 B          => total 80384 B

    const int tid = threadIdx.x;
    const int tx = tid & 31, ty = tid >> 5;
    const int T0 = blockIdx.x * 128;

    for (int i = tid; i < (K_IN*HCH)/4; i += 256)
        ((float4*)Ut)[i] = ((const float4*)Ug)[i];
    {
        const float4* xg = (const float4*)(x + (size_t)T0 * K_IN);
        for (int i = tid; i < (128*K_IN)/4; i += 256)
            ((float4*)xs)[i] = xg[i];
    }
    for (int i = tid; i < CCH*HCH; i += 256) Vl[i] = Wfin[i];
    __syncthreads();

    const int j0 = tx*4;
    const int tb = ty*16;
    float acc[16][4];
#pragma unroll
    for (int t = 0; t < 16; ++t)
#pragma unroll
        for (int q = 0; q < 4; ++q) acc[t][q] = 0.f;

    for (int kc = 0; kc < 19; ++kc) {
        const float4 u0 = *(const float4*)&Ut[(4*kc+0)*HCH + j0];
        const float4 u1 = *(const float4*)&Ut[(4*kc+1)*HCH + j0];
        const float4 u2 = *(const float4*)&Ut[(4*kc+2)*HCH + j0];
        const float4 u3 = *(const float4*)&Ut[(4*kc+3)*HCH + j0];
#pragma unroll
        for (int ti = 0; ti < 16; ++ti) {
            const float4 xv = *(const float4*)&xs[(tb+ti)*K_IN + 4*kc];
            acc[ti][0] = fmaf(xv.x, u0.x, acc[ti][0]);
            acc[ti][1] = fmaf(xv.x, u0.y, acc[ti][1]);
            acc[ti][2] = fmaf(xv.x, u0.z, acc[ti][2]);
            acc[ti][3] = fmaf(xv.x, u0.w, acc[ti][3]);
            acc[ti][0] = fmaf(xv.y, u1.x, acc[ti][0]);
            acc[ti][1] = fmaf(xv.y, u1.y, acc[ti][1]);
            acc[ti][2] = fmaf(xv.y, u1.z, acc[ti][2]);
            acc[ti][3] = fmaf(xv.y, u1.w, acc[ti][3]);
            acc[ti][0] = fmaf(xv.z, u2.x, acc[ti][0]);
            acc[ti][1] = fmaf(xv.z, u2.y, acc[ti][1]);
            acc[ti][2] = fmaf(xv.z, u2.z, acc[ti][2]);
            acc[ti][3] = fmaf(xv.z, u2.w, acc[ti][3]);
            acc[ti][0] = fmaf(xv.w, u3.x, acc[ti][0]);
            acc[ti][1] = fmaf(xv.w, u3.y, acc[ti][1]);
            acc[ti][2] = fmaf(xv.w, u3.z, acc[ti][2]);
            acc[ti][3] = fmaf(xv.w, u3.w, acc[ti][3]);
        }
    }

    // ---- epilogue: relu, x5 matmul partials, LDS reduce over 32 tx lanes ----
    const float4 cv = *(const float4*)&cg[j0];
    float* opp = xs;                 // [256][21] partials (stride 21, coprime 32)
    float* opf = Ut;                 // [640] final block outputs
    __syncthreads();                 // all Ut/xs reads done

    for (int tg = 0; tg < 4; ++tg) {
        float oa[20];
#pragma unroll
        for (int s = 0; s < 4; ++s) {
            const int ti = tg*4 + s;
            const float h0 = fmaxf(acc[ti][0] + cv.x, 0.f);
            const float h1 = fmaxf(acc[ti][1] + cv.y, 0.f);
            const float h2 = fmaxf(acc[ti][2] + cv.z, 0.f);
            const float h3 = fmaxf(acc[ti][3] + cv.w, 0.f);
#pragma unroll
            for (int m = 0; m < CCH; ++m)
                oa[s*5+m] = h0*Vl[m*HCH + j0]     + h1*Vl[m*HCH + j0 + 1]
                          + h2*Vl[m*HCH + j0 + 2] + h3*Vl[m*HCH + j0 + 3];
        }
#pragma unroll
        for (int i = 0; i < 20; ++i) opp[tid*21 + i] = oa[i];
        __syncthreads();
        if (tid < 160) {
            const int typ = tid / 20, rem = tid % 20;   // rem = s*5+m
            float s = 0.f;
            for (int xx = 0; xx < 32; ++xx)
                s += opp[(typ*32 + xx)*21 + rem];
            opf[(typ*16 + tg*4)*5 + rem] = s;
        }
        __syncthreads();
    }

    if (tid < 160) {
        const int gi = tid*4;
        float4 v = *(const float4*)&opf[gi];
        v.x += bfin[(gi+0) % 5]; v.y += bfin[(gi+1) % 5];
        v.z += bfin[(gi+2) % 5]; v.w += bfin[(gi+3) % 5];
        *(float4*)&out[(size_t)T0*CCH + gi] = v;
    }
}

extern "C" void kernel_launch(void* const* d_in, const int* in_sizes, int n_in,
                              void* d_out, int out_size, void* d_ws, size_t ws_size,
                              hipStream_t stream)
{
    (void)in_sizes; (void)n_in; (void)out_size; (void)ws_size;
    const float* x    = (const float*)d_in[0];
    const float* Wode = (const float*)d_in[1];
    const float* bode = (const float*)d_in[2];
    const float* Wpen = (const float*)d_in[3];
    const float* bpen = (const float*)d_in[4];
    const float* Wfin = (const float*)d_in[5];
    const float* bfin = (const float*)d_in[6];
    float* out = (float*)d_out;
    float* wsf = (float*)d_ws;
    unsigned* ctr = (unsigned*)(wsf + OFF_CTRF);

    hipMemsetAsync(ctr, 0, 64, stream);
    chain_kernel<<<dim3(NCHB), dim3(256), 0, stream>>>(Wode, bode, Wpen, bpen,
                                                       wsf, ctr);
    main_kernel<<<dim3(512), dim3(256), 0, stream>>>(x, wsf + OFF_U, wsf + OFF_C,
                                                     Wfin, bfin, out);
}

// Round 5
// 49.592 us; speedup vs baseline: 2.9163x; 1.4114x over previous
//
#include <hip/hip_runtime.h>

#define K_IN 76      // input feature dim
#define DD 84        // augmented dim
#define HCH 128      // penultimate width
#define CCH 5        // classes

#define LW  92       // Wf LDS stride (16B-aligned, good bank spread)
#define LR  92       // row-buffer stride (16B-aligned)
#define LP  85       // WpenL stride (odd -> conflict-free scalar reads)

// ws float offsets
#define OFF_U 0              // U [76][128]
#define OFF_C (K_IN*HCH)     // c [128]

#define NBLK 7               // chain blocks (each owns 12 rows of exp(K))

// E-term coefficients 1/n! for n=2..9 (step s computes K^{s+2})
__device__ __constant__ float CE[8] = {
    0.5f, 1.f/6.f, 1.f/24.f, 1.f/120.f, 1.f/720.f, 1.f/5040.f,
    1.f/40320.f, 1.f/362880.f };
// phi1 coefficients 1/(n+1)! for v_n, n=1..9 (step s computes v_{s+1})
__device__ __constant__ float PH[9] = {
    0.5f, 1.f/6.f, 1.f/24.f, 1.f/120.f, 1.f/720.f, 1.f/5040.f,
    1.f/40320.f, 1.f/362880.f, 1.f/3628800.f };

// ---------------- precompute chain: 7 independent blocks, no global sync ----
// Block b computes rows i0..i0+11 (i0=12b) of (E+I), E = deg-9 Taylor exp(K),
// K = W^T, via row recurrence r_{n+1} = r_n * K  (K columns = W rows = Wf).
// Then U[k][:] = (E+I)[k][:] * Wpen^T locally. qv/c done by block 0.
__global__ __launch_bounds__(256) void chain_kernel(
    const float* __restrict__ W,     // [84][84]
    const float* __restrict__ bode,  // [84]
    const float* __restrict__ Wpen,  // [128][84]
    const float* __restrict__ bpen,  // [128]
    float* __restrict__ ws)
{
    __shared__ float Wf[DD*LW];        // W row-major (= K^T rows)   30.9 KB
    __shared__ float WpenL[HCH*LP];    // Wpen rows                  43.5 KB
    __shared__ float r0[12*LR], r1[12*LR];                        //  8.8 KB
    __shared__ float vq[88], qvL[88];

    const int tid = threadIdx.x;
    const int i0 = blockIdx.x * 12;
    const int j84 = tid % 84;          // column / Wf-row owned (recurrence, qv)
    const int pg  = tid / 84;          // 0..2 -> p group of 4 rows
    const bool act = (tid < 252);

    // ---- stage Wf (= W, row-major, stride LW) and WpenL; vq = bode ----
    for (int e = tid; e < 1764; e += 256) {          // 84*84/4
        float4 v = ((const float4*)W)[e];
        int r = e / 21, c4 = (e % 21) * 4;
        *(float4*)&Wf[r*LW + c4] = v;
    }
    for (int e = tid; e < 2688; e += 256) {          // 128*84/4
        float4 v = ((const float4*)Wpen)[e];
        int r = e / 21, c4 = (e % 21) * 4;
        WpenL[r*LP + c4 + 0] = v.x; WpenL[r*LP + c4 + 1] = v.y;
        WpenL[r*LP + c4 + 2] = v.z; WpenL[r*LP + c4 + 3] = v.w;
    }
    if (tid < DD) vq[tid] = bode[tid];
    __syncthreads();

    // ---- per-thread register copy of Wf row j84 (static indexing only) ----
    float wfreg[DD];
#pragma unroll
    for (int m = 0; m < DD; ++m) wfreg[m] = Wf[j84*LW + m];

    // ---- init: r0 rows = K[i0+p][:] = Wf[:, i0+p] ; racc = 2I + K rows ----
    for (int e = tid; e < 1008; e += 256) {          // 12*84
        int p = e / 84, k = e - p*84;
        r0[p*LR + k] = Wf[k*LW + (i0 + p)];
    }
    float racc[4];
#pragma unroll
    for (int q = 0; q < 4; ++q) {
        const int i = i0 + pg*4 + q;
        racc[q] = act ? (2.f*(i == j84) + Wf[j84*LW + i]) : 0.f;
    }
    float qacc = (tid < DD) ? vq[tid] : 0.f;         // phi1 term n=0 (coef 1)

    // ---- 8 recurrence steps: v_{s+2} = v_{s+1} * K ; racc += CE[s]*v ----
    float* rc = r0;
    float* rn = r1;
#pragma unroll 1
    for (int s = 0; s < 8; ++s) {
        __syncthreads();
        const float cf = CE[s];
        if (act) {
#pragma unroll
            for (int q = 0; q < 4; ++q) {
                const int p = pg*4 + q;
                float a0 = 0.f, a1 = 0.f, a2 = 0.f, a3 = 0.f;
#pragma unroll
                for (int kg = 0; kg < 21; ++kg) {
                    const float4 rv = *(const float4*)&rc[p*LR + kg*4];
                    a0 = fmaf(rv.x, wfreg[kg*4+0], a0);
                    a1 = fmaf(rv.y, wfreg[kg*4+1], a1);
                    a2 = fmaf(rv.z, wfreg[kg*4+2], a2);
                    a3 = fmaf(rv.w, wfreg[kg*4+3], a3);
                }
                const float d = (a0 + a1) + (a2 + a3);
                rn[p*LR + j84] = d;
                racc[q] = fmaf(cf, d, racc[q]);
            }
        }
        float* t = rc; rc = rn; rn = t;
    }
    __syncthreads();

    // ---- dump racc rows into r1 (v8 buffer, dead) for the fold ----
    float* raccL = r1;
    if (act) {
#pragma unroll
        for (int q = 0; q < 4; ++q)
            raccL[(pg*4 + q)*LR + j84] = racc[q];
    }

    // ---- qv = b * phi1(K), deg-9 (redundant per block; trivial) ----
#pragma unroll 1
    for (int s = 0; s < 9; ++s) {
        __syncthreads();
        float nv = 0.f;
        if (tid < DD) {
#pragma unroll
            for (int kg = 0; kg < 21; ++kg) {
                const float4 vv = *(const float4*)&vq[kg*4];
                nv = fmaf(vv.x, wfreg[kg*4+0], nv);
                nv = fmaf(vv.y, wfreg[kg*4+1], nv);
                nv = fmaf(vv.z, wfreg[kg*4+2], nv);
                nv = fmaf(vv.w, wfreg[kg*4+3], nv);
            }
        }
        __syncthreads();
        if (tid < DD) { vq[tid] = nv; qacc = fmaf(PH[s], nv, qacc); }
    }
    if (tid < DD) qvL[tid] = qacc;
    __syncthreads();

    // ---- fold: U[i0+p][j] = sum_m raccL[p][m] * Wpen[j][m] ----
    const int j = tid & 127;
    const int half = tid >> 7;                       // 0: p 0..5, 1: p 6..11
    float wp[DD];
#pragma unroll
    for (int m = 0; m < DD; ++m) wp[m] = WpenL[j*LP + m];

#pragma unroll
    for (int pp = 0; pp < 6; ++pp) {
        const int p = half*6 + pp;
        const int krow = i0 + p;
        float acc = 0.f;
#pragma unroll
        for (int mg = 0; mg < 21; ++mg) {
            const float4 rv = *(const float4*)&raccL[p*LR + mg*4];
            acc = fmaf(rv.x, wp[mg*4+0], acc);
            acc = fmaf(rv.y, wp[mg*4+1], acc);
            acc = fmaf(rv.z, wp[mg*4+2], acc);
            acc = fmaf(rv.w, wp[mg*4+3], acc);
        }
        if (krow < K_IN) ws[OFF_U + krow*HCH + j] = acc;
    }

    // ---- c[j] = bpen[j] + sum_m qv[m]*Wpen[j][m]  (block 0 only) ----
    if (blockIdx.x == 0 && half == 0) {
        float cc = bpen[j];
#pragma unroll
        for (int mg = 0; mg < 21; ++mg) {
            const float4 qv4 = *(const float4*)&qvL[mg*4];
            cc = fmaf(qv4.x, wp[mg*4+0], cc);
            cc = fmaf(qv4.y, wp[mg*4+1], cc);
            cc = fmaf(qv4.z, wp[mg*4+2], cc);
            cc = fmaf(qv4.w, wp[mg*4+3], cc);
        }
        ws[OFF_C + j] = cc;
    }
}

// ---------------- main fused kernel (verified round 4, unchanged) ----------
// out[t] = relu(x[t]*U + c) * Wfin^T + bfin
// 512 blocks x 256 thr; block = 128 tokens; thread = 16 tokens x 4 j.
__global__ __launch_bounds__(256) void main_kernel(
    const float* __restrict__ x,     // [65536][76]
    const float* __restrict__ Ug,    // [76][128]
    const float* __restrict__ cg,    // [128]
    const float* __restrict__ Wfin,  // [5][128]
    const float* __restrict__ bfin,  // [5]
    float* __restrict__ out)         // [65536][5]
{
    __shared__ float Ut[K_IN*HCH];   // 38912 B ; reused as final out tile
    __shared__ float xs[128*K_IN];   // 38912 B ; reused as opp[256*21]
    __shared__ float Vl[CCH*HCH];    // 2560 B

    const int tid = threadIdx.x;
    const int tx = tid & 31, ty = tid >> 5;
    const int T0 = blockIdx.x * 128;

    for (int i = tid; i < (K_IN*HCH)/4; i += 256)
        ((float4*)Ut)[i] = ((const float4*)Ug)[i];
    {
        const float4* xg = (const float4*)(x + (size_t)T0 * K_IN);
        for (int i = tid; i < (128*K_IN)/4; i += 256)
            ((float4*)xs)[i] = xg[i];
    }
    for (int i = tid; i < CCH*HCH; i += 256) Vl[i] = Wfin[i];
    __syncthreads();

    const int j0 = tx*4;
    const int tb = ty*16;
    float acc[16][4];
#pragma unroll
    for (int t = 0; t < 16; ++t)
#pragma unroll
        for (int q = 0; q < 4; ++q) acc[t][q] = 0.f;

    for (int kc = 0; kc < 19; ++kc) {
        const float4 u0 = *(const float4*)&Ut[(4*kc+0)*HCH + j0];
        const float4 u1 = *(const float4*)&Ut[(4*kc+1)*HCH + j0];
        const float4 u2 = *(const float4*)&Ut[(4*kc+2)*HCH + j0];
        const float4 u3 = *(const float4*)&Ut[(4*kc+3)*HCH + j0];
#pragma unroll
        for (int ti = 0; ti < 16; ++ti) {
            const float4 xv = *(const float4*)&xs[(tb+ti)*K_IN + 4*kc];
            acc[ti][0] = fmaf(xv.x, u0.x, acc[ti][0]);
            acc[ti][1] = fmaf(xv.x, u0.y, acc[ti][1]);
            acc[ti][2] = fmaf(xv.x, u0.z, acc[ti][2]);
            acc[ti][3] = fmaf(xv.x, u0.w, acc[ti][3]);
            acc[ti][0] = fmaf(xv.y, u1.x, acc[ti][0]);
            acc[ti][1] = fmaf(xv.y, u1.y, acc[ti][1]);
            acc[ti][2] = fmaf(xv.y, u1.z, acc[ti][2]);
            acc[ti][3] = fmaf(xv.y, u1.w, acc[ti][3]);
            acc[ti][0] = fmaf(xv.z, u2.x, acc[ti][0]);
            acc[ti][1] = fmaf(xv.z, u2.y, acc[ti][1]);
            acc[ti][2] = fmaf(xv.z, u2.z, acc[ti][2]);
            acc[ti][3] = fmaf(xv.z, u2.w, acc[ti][3]);
            acc[ti][0] = fmaf(xv.w, u3.x, acc[ti][0]);
            acc[ti][1] = fmaf(xv.w, u3.y, acc[ti][1]);
            acc[ti][2] = fmaf(xv.w, u3.z, acc[ti][2]);
            acc[ti][3] = fmaf(xv.w, u3.w, acc[ti][3]);
        }
    }

    // ---- epilogue: relu, x5 matmul partials, LDS reduce over 32 tx lanes ----
    const float4 cv = *(const float4*)&cg[j0];
    float* opp = xs;                 // [256][21] partials (stride 21, coprime 32)
    float* opf = Ut;                 // [640] final block outputs
    __syncthreads();

    for (int tg = 0; tg < 4; ++tg) {
        float oa[20];
#pragma unroll
        for (int s = 0; s < 4; ++s) {
            const int ti = tg*4 + s;
            const float h0 = fmaxf(acc[ti][0] + cv.x, 0.f);
            const float h1 = fmaxf(acc[ti][1] + cv.y, 0.f);
            const float h2 = fmaxf(acc[ti][2] + cv.z, 0.f);
            const float h3 = fmaxf(acc[ti][3] + cv.w, 0.f);
#pragma unroll
            for (int m = 0; m < CCH; ++m)
                oa[s*5+m] = h0*Vl[m*HCH + j0]     + h1*Vl[m*HCH + j0 + 1]
                          + h2*Vl[m*HCH + j0 + 2] + h3*Vl[m*HCH + j0 + 3];
        }
#pragma unroll
        for (int i = 0; i < 20; ++i) opp[tid*21 + i] = oa[i];
        __syncthreads();
        if (tid < 160) {
            const int typ = tid / 20, rem = tid % 20;   // rem = s*5+m
            float s = 0.f;
            for (int xx = 0; xx < 32; ++xx)
                s += opp[(typ*32 + xx)*21 + rem];
            opf[(typ*16 + tg*4)*5 + rem] = s;
        }
        __syncthreads();
    }

    if (tid < 160) {
        const int gi = tid*4;
        float4 v = *(const float4*)&opf[gi];
        v.x += bfin[(gi+0) % 5]; v.y += bfin[(gi+1) % 5];
        v.z += bfin[(gi+2) % 5]; v.w += bfin[(gi+3) % 5];
        *(float4*)&out[(size_t)T0*CCH + gi] = v;
    }
}

extern "C" void kernel_launch(void* const* d_in, const int* in_sizes, int n_in,
                              void* d_out, int out_size, void* d_ws, size_t ws_size,
                              hipStream_t stream)
{
    (void)in_sizes; (void)n_in; (void)out_size; (void)ws_size;
    const float* x    = (const float*)d_in[0];
    const float* Wode = (const float*)d_in[1];
    const float* bode = (const float*)d_in[2];
    const float* Wpen = (const float*)d_in[3];
    const float* bpen = (const float*)d_in[4];
    const float* Wfin = (const float*)d_in[5];
    const float* bfin = (const float*)d_in[6];
    float* out = (float*)d_out;
    float* wsf = (float*)d_ws;

    chain_kernel<<<dim3(NBLK), dim3(256), 0, stream>>>(Wode, bode, Wpen, bpen, wsf);
    main_kernel<<<dim3(512), dim3(256), 0, stream>>>(x, wsf + OFF_U, wsf + OFF_C,
                                                     Wfin, bfin, out);
}

// Round 6
// 35.744 us; speedup vs baseline: 4.0461x; 1.3874x over previous
//
#include <hip/hip_runtime.h>

#define K_IN 76      // input feature dim
#define DD 84        // augmented dim
#define HCH 128      // penultimate width
#define CCH 5        // classes

#define LW 92        // Wf LDS stride (floats; 16B-aligned rows)
#define LR 92        // row-buffer stride

// ws float offsets
#define OFF_U 0              // U [76][128]
#define OFF_C (K_IN*HCH)     // c [128]

#define NROW 3               // E-rows per block
#define NBLK 27              // block 0: qv+c ; blocks 1..26: 3 rows each

// E-term coefficients 1/n! for n=2..9 (step s adds K^{s+2})
__device__ __constant__ float CE[8] = {
    0.5f, 1.f/6.f, 1.f/24.f, 1.f/120.f, 1.f/720.f, 1.f/5040.f,
    1.f/40320.f, 1.f/362880.f };
// phi1 coefficients 1/(n+2)! for step s (adds v_{s+1})
__device__ __constant__ float PH[9] = {
    0.5f, 1.f/6.f, 1.f/24.f, 1.f/120.f, 1.f/720.f, 1.f/5040.f,
    1.f/40320.f, 1.f/362880.f, 1.f/3628800.f };

// ---------------- precompute: 27 independent blocks, no cross-block sync ----
// K = W^T. Block b>=1 computes rows i0..i0+2 (i0=3(b-1)) of (E+I), E=exp(K)
// deg-9 Taylor, via row recurrence r_{n+1} = r_n*K; then folds those rows of
// U = (E+I)*Wpen^T. Block 0 computes qv = b*phi1(K) and c = qv*Wpen^T + bpen.
__global__ __launch_bounds__(256) void chain_kernel(
    const float* __restrict__ W,     // [84][84]
    const float* __restrict__ bode,  // [84]
    const float* __restrict__ Wpen,  // [128][84]
    const float* __restrict__ bpen,  // [128]
    float* __restrict__ ws)
{
    __shared__ float Wf[DD*LW];      // W row-major (row j = K column j) 30.9KB
    __shared__ float r0[NROW*LR], r1[NROW*LR];
    __shared__ float vq[88];

    const int tid = threadIdx.x;
    const int j84 = tid % 84;        // owned column
    const int pg  = tid / 84;        // owned row within slice (0..2)
    const bool act = (tid < 252);

    // ---- stage Wf = W (row-major, stride LW) ----
    for (int e = tid; e < 1764; e += 256) {
        float4 v = ((const float4*)W)[e];
        int r = e / 21, c4 = (e % 21) * 4;
        *(float4*)&Wf[r*LW + c4] = v;
    }
    __syncthreads();

    // ---- per-thread K-column j84 in registers (b128 loads, ~2-way max) ----
    float wfreg[DD];
#pragma unroll
    for (int mg = 0; mg < 21; ++mg) {
        float4 v = *(const float4*)&Wf[j84*LW + mg*4];
        wfreg[mg*4+0] = v.x; wfreg[mg*4+1] = v.y;
        wfreg[mg*4+2] = v.z; wfreg[mg*4+3] = v.w;
    }

    if (blockIdx.x == 0) {
        // ================= qv = b*phi1(K), deg-9 =================
        if (tid < DD) vq[tid] = bode[tid];
        __syncthreads();
        float qacc = (tid < DD) ? vq[tid] : 0.f;
#pragma unroll 1
        for (int s = 0; s < 9; ++s) {
            float nv = 0.f;
            if (tid < DD) {
                float a0 = 0.f, a1 = 0.f, a2 = 0.f, a3 = 0.f;
#pragma unroll
                for (int mg = 0; mg < 21; ++mg) {
                    const float4 vv = *(const float4*)&vq[mg*4];
                    a0 = fmaf(vv.x, wfreg[mg*4+0], a0);
                    a1 = fmaf(vv.y, wfreg[mg*4+1], a1);
                    a2 = fmaf(vv.z, wfreg[mg*4+2], a2);
                    a3 = fmaf(vv.w, wfreg[mg*4+3], a3);
                }
                nv = (a0 + a1) + (a2 + a3);
            }
            __syncthreads();
            if (tid < DD) { vq[tid] = nv; qacc = fmaf(PH[s], nv, qacc); }
            __syncthreads();
        }
        if (tid < DD) vq[tid] = qacc;          // vq = qv
        __syncthreads();

        // ================= c[j] = bpen[j] + qv . Wpen[j][:] =================
        if (tid < HCH) {
            float wp[DD];
#pragma unroll
            for (int mg = 0; mg < 21; ++mg) {
                float4 v = *(const float4*)&Wpen[tid*DD + mg*4];
                wp[mg*4+0] = v.x; wp[mg*4+1] = v.y;
                wp[mg*4+2] = v.z; wp[mg*4+3] = v.w;
            }
            float cc = bpen[tid];
#pragma unroll
            for (int mg = 0; mg < 21; ++mg) {
                const float4 q4 = *(const float4*)&vq[mg*4];
                cc = fmaf(q4.x, wp[mg*4+0], cc);
                cc = fmaf(q4.y, wp[mg*4+1], cc);
                cc = fmaf(q4.z, wp[mg*4+2], cc);
                cc = fmaf(q4.w, wp[mg*4+3], cc);
            }
            ws[OFF_C + tid] = cc;
        }
        return;
    }

    // ================= rows i0..i0+2 of (E+I) =================
    const int i0 = (blockIdx.x - 1) * NROW;

    // r0 rows = K[i0+p][:] = Wf[:, i0+p]
    for (int e = tid; e < NROW*DD; e += 256) {
        int p = e / DD, k = e - p*DD;
        r0[p*LR + k] = Wf[k*LW + i0 + p];
    }
    // racc = (2I + K)[i0+pg][j84]
    float racc = 0.f;
    if (act)
        racc = ((i0 + pg) == j84 ? 2.f : 0.f) + Wf[j84*LW + i0 + pg];
    __syncthreads();

    // 8 steps: v_{s+2} = v_{s+1}*K ; racc += CE[s]*v
    float* rc = r0;
    float* rn = r1;
#pragma unroll 1
    for (int s = 0; s < 8; ++s) {
        float d = 0.f;
        if (act) {
            float a0 = 0.f, a1 = 0.f, a2 = 0.f, a3 = 0.f;
#pragma unroll
            for (int mg = 0; mg < 21; ++mg) {
                const float4 rv = *(const float4*)&rc[pg*LR + mg*4];
                a0 = fmaf(rv.x, wfreg[mg*4+0], a0);
                a1 = fmaf(rv.y, wfreg[mg*4+1], a1);
                a2 = fmaf(rv.z, wfreg[mg*4+2], a2);
                a3 = fmaf(rv.w, wfreg[mg*4+3], a3);
            }
            d = (a0 + a1) + (a2 + a3);
        }
        __syncthreads();
        if (act) { rn[pg*LR + j84] = d; racc = fmaf(CE[s], d, racc); }
        __syncthreads();
        float* t = rc; rc = rn; rn = t;
    }

    // publish racc rows (rn buffer is dead)
    if (act) rn[pg*LR + j84] = racc;
    __syncthreads();

    // ================= fold: U[i0+p][j] = racc_row_p . Wpen[j][:] ==========
    const int j = tid & 127;
    const int hh = tid >> 7;
    float wp[DD];
#pragma unroll
    for (int mg = 0; mg < 21; ++mg) {
        float4 v = *(const float4*)&Wpen[j*DD + mg*4];
        wp[mg*4+0] = v.x; wp[mg*4+1] = v.y;
        wp[mg*4+2] = v.z; wp[mg*4+3] = v.w;
    }
#pragma unroll
    for (int pi = 0; pi < 2; ++pi) {
        const int p = hh + 2*pi;               // hh=0: p=0,2 ; hh=1: p=1
        if (p < NROW) {
            const int krow = i0 + p;
            float acc = 0.f;
#pragma unroll
            for (int mg = 0; mg < 21; ++mg) {
                const float4 rv = *(const float4*)&rn[p*LR + mg*4];
                acc = fmaf(rv.x, wp[mg*4+0], acc);
                acc = fmaf(rv.y, wp[mg*4+1], acc);
                acc = fmaf(rv.z, wp[mg*4+2], acc);
                acc = fmaf(rv.w, wp[mg*4+3], acc);
            }
            if (krow < K_IN) ws[OFF_U + krow*HCH + j] = acc;
        }
    }
}

// ---------------- main fused kernel (verified round 4, unchanged) ----------
// out[t] = relu(x[t]*U + c) * Wfin^T + bfin
// 512 blocks x 256 thr; block = 128 tokens; thread = 16 tokens x 4 j.
__global__ __launch_bounds__(256) void main_kernel(
    const float* __restrict__ x,     // [65536][76]
    const float* __restrict__ Ug,    // [76][128]
    const float* __restrict__ cg,    // [128]
    const float* __restrict__ Wfin,  // [5][128]
    const float* __restrict__ bfin,  // [5]
    float* __restrict__ out)         // [65536][5]
{
    __shared__ float Ut[K_IN*HCH];   // 38912 B ; reused as final out tile
    __shared__ float xs[128*K_IN];   // 38912 B ; reused as opp[256*21]
    __shared__ float Vl[CCH*HCH];    // 2560 B

    const int tid = threadIdx.x;
    const int tx = tid & 31, ty = tid >> 5;
    const int T0 = blockIdx.x * 128;

    for (int i = tid; i < (K_IN*HCH)/4; i += 256)
        ((float4*)Ut)[i] = ((const float4*)Ug)[i];
    {
        const float4* xg = (const float4*)(x + (size_t)T0 * K_IN);
        for (int i = tid; i < (128*K_IN)/4; i += 256)
            ((float4*)xs)[i] = xg[i];
    }
    for (int i = tid; i < CCH*HCH; i += 256) Vl[i] = Wfin[i];
    __syncthreads();

    const int j0 = tx*4;
    const int tb = ty*16;
    float acc[16][4];
#pragma unroll
    for (int t = 0; t < 16; ++t)
#pragma unroll
        for (int q = 0; q < 4; ++q) acc[t][q] = 0.f;

    for (int kc = 0; kc < 19; ++kc) {
        const float4 u0 = *(const float4*)&Ut[(4*kc+0)*HCH + j0];
        const float4 u1 = *(const float4*)&Ut[(4*kc+1)*HCH + j0];
        const float4 u2 = *(const float4*)&Ut[(4*kc+2)*HCH + j0];
        const float4 u3 = *(const float4*)&Ut[(4*kc+3)*HCH + j0];
#pragma unroll
        for (int ti = 0; ti < 16; ++ti) {
            const float4 xv = *(const float4*)&xs[(tb+ti)*K_IN + 4*kc];
            acc[ti][0] = fmaf(xv.x, u0.x, acc[ti][0]);
            acc[ti][1] = fmaf(xv.x, u0.y, acc[ti][1]);
            acc[ti][2] = fmaf(xv.x, u0.z, acc[ti][2]);
            acc[ti][3] = fmaf(xv.x, u0.w, acc[ti][3]);
            acc[ti][0] = fmaf(xv.y, u1.x, acc[ti][0]);
            acc[ti][1] = fmaf(xv.y, u1.y, acc[ti][1]);
            acc[ti][2] = fmaf(xv.y, u1.z, acc[ti][2]);
            acc[ti][3] = fmaf(xv.y, u1.w, acc[ti][3]);
            acc[ti][0] = fmaf(xv.z, u2.x, acc[ti][0]);
            acc[ti][1] = fmaf(xv.z, u2.y, acc[ti][1]);
            acc[ti][2] = fmaf(xv.z, u2.z, acc[ti][2]);
            acc[ti][3] = fmaf(xv.z, u2.w, acc[ti][3]);
            acc[ti][0] = fmaf(xv.w, u3.x, acc[ti][0]);
            acc[ti][1] = fmaf(xv.w, u3.y, acc[ti][1]);
            acc[ti][2] = fmaf(xv.w, u3.z, acc[ti][2]);
            acc[ti][3] = fmaf(xv.w, u3.w, acc[ti][3]);
        }
    }

    // ---- epilogue: relu, x5 matmul partials, LDS reduce over 32 tx lanes ----
    const float4 cv = *(const float4*)&cg[j0];
    float* opp = xs;                 // [256][21] partials (stride 21, coprime 32)
    float* opf = Ut;                 // [640] final block outputs
    __syncthreads();

    for (int tg = 0; tg < 4; ++tg) {
        float oa[20];
#pragma unroll
        for (int s = 0; s < 4; ++s) {
            const int ti = tg*4 + s;
            const float h0 = fmaxf(acc[ti][0] + cv.x, 0.f);
            const float h1 = fmaxf(acc[ti][1] + cv.y, 0.f);
            const float h2 = fmaxf(acc[ti][2] + cv.z, 0.f);
            const float h3 = fmaxf(acc[ti][3] + cv.w, 0.f);
#pragma unroll
            for (int m = 0; m < CCH; ++m)
                oa[s*5+m] = h0*Vl[m*HCH + j0]     + h1*Vl[m*HCH + j0 + 1]
                          + h2*Vl[m*HCH + j0 + 2] + h3*Vl[m*HCH + j0 + 3];
        }
#pragma unroll
        for (int i = 0; i < 20; ++i) opp[tid*21 + i] = oa[i];
        __syncthreads();
        if (tid < 160) {
            const int typ = tid / 20, rem = tid % 20;   // rem = s*5+m
            float s = 0.f;
            for (int xx = 0; xx < 32; ++xx)
                s += opp[(typ*32 + xx)*21 + rem];
            opf[(typ*16 + tg*4)*5 + rem] = s;
        }
        __syncthreads();
    }

    if (tid < 160) {
        const int gi = tid*4;
        float4 v = *(const float4*)&opf[gi];
        v.x += bfin[(gi+0) % 5]; v.y += bfin[(gi+1) % 5];
        v.z += bfin[(gi+2) % 5]; v.w += bfin[(gi+3) % 5];
        *(float4*)&out[(size_t)T0*CCH + gi] = v;
    }
}

extern "C" void kernel_launch(void* const* d_in, const int* in_sizes, int n_in,
                              void* d_out, int out_size, void* d_ws, size_t ws_size,
                              hipStream_t stream)
{
    (void)in_sizes; (void)n_in; (void)out_size; (void)ws_size;
    const float* x    = (const float*)d_in[0];
    const float* Wode = (const float*)d_in[1];
    const float* bode = (const float*)d_in[2];
    const float* Wpen = (const float*)d_in[3];
    const float* bpen = (const float*)d_in[4];
    const float* Wfin = (const float*)d_in[5];
    const float* bfin = (const float*)d_in[6];
    float* out = (float*)d_out;
    float* wsf = (float*)d_ws;

    chain_kernel<<<dim3(NBLK), dim3(256), 0, stream>>>(Wode, bode, Wpen, bpen, wsf);
    main_kernel<<<dim3(512), dim3(256), 0, stream>>>(x, wsf + OFF_U, wsf + OFF_C,
                                                     Wfin, bfin, out);
}